// Round 3
// baseline (225.409 us; speedup 1.0000x reference)
//
#include <hip/hip_runtime.h>
#include <stdint.h>

typedef __bf16 bf16;
typedef __attribute__((ext_vector_type(8))) __bf16 bf16x8;
typedef __attribute__((ext_vector_type(4))) float f32x4;

#define SEQ   2048
#define DM    1024
#define NH    16
#define HD    64
#define MROWS 4096   // B*L

__device__ __forceinline__ void glds16(const bf16* g, bf16* l) {
  __builtin_amdgcn_global_load_lds(
      (__attribute__((address_space(1))) unsigned int*)(g),
      (__attribute__((address_space(3))) unsigned int*)(l),
      16, 0, 0);
}

static __device__ __forceinline__ bf16x8 cvt_f32x8(const float* __restrict__ p) {
  const f32x4 a = *(const f32x4*)p;
  const f32x4 b = *(const f32x4*)(p + 4);
  bf16x8 r;
  r[0] = (bf16)a[0]; r[1] = (bf16)a[1]; r[2] = (bf16)a[2]; r[3] = (bf16)a[3];
  r[4] = (bf16)b[0]; r[5] = (bf16)b[1]; r[6] = (bf16)b[2]; r[7] = (bf16)b[3];
  return r;
}

// ---------------------------------------------------------------------------
// One-pass fp32->bf16 conversion of all 7 tensors (q,k,v,Wq,Wk,Wv,Wo).
// ---------------------------------------------------------------------------
__global__ void conv_all(
    const float* __restrict__ q, const float* __restrict__ k, const float* __restrict__ v,
    const float* __restrict__ wq, const float* __restrict__ wk,
    const float* __restrict__ wv, const float* __restrict__ wo,
    bf16* __restrict__ dq, bf16* __restrict__ dk, bf16* __restrict__ dv,
    bf16* __restrict__ dwq, bf16* __restrict__ dwk, bf16* __restrict__ dwv,
    bf16* __restrict__ dwo)
{
  const size_t c = (size_t)blockIdx.x * 256 + threadIdx.x;
  const float* s; bf16* d; size_t off;
  if (c < 524288)        { s = q;  d = dq;  off = c; }
  else if (c < 1048576)  { s = k;  d = dk;  off = c - 524288; }
  else if (c < 1572864)  { s = v;  d = dv;  off = c - 1048576; }
  else if (c < 1703936)  { s = wq; d = dwq; off = c - 1572864; }
  else if (c < 1835008)  { s = wk; d = dwk; off = c - 1703936; }
  else if (c < 1966080)  { s = wv; d = dwv; off = c - 1835008; }
  else                   { s = wo; d = dwo; off = c - 1966080; }
  *(bf16x8*)(d + off * 8) = cvt_f32x8(s + off * 8);
}

// ---------------------------------------------------------------------------
// Fused QKV projection, all-bf16, single-buffered (32 KB LDS, 4 blocks/CU).
// z=0: Qh = (q@Wq^T+bq)*(0.125*log2e) head layout (attn uses exp2);
// z=1: Kh; z=2: Vt = Wv@v^T+bv, [B,H,64,SEQ] with key'=(l&15)*8+((l>>4)&7).
// ---------------------------------------------------------------------------
__global__ __launch_bounds__(256, 4) void proj_qkv(
    const bf16* __restrict__ qb, const bf16* __restrict__ kb, const bf16* __restrict__ vb,
    const bf16* __restrict__ Wqb, const bf16* __restrict__ Wkb, const bf16* __restrict__ Wvb,
    const float* __restrict__ bq, const float* __restrict__ bk, const float* __restrict__ bv,
    bf16* __restrict__ Qh, bf16* __restrict__ Kh, bf16* __restrict__ Vt)
{
  __shared__ __align__(16) bf16 sA[128 * 64];
  __shared__ __align__(16) bf16 sB[128 * 64];

  const int z = blockIdx.z;
  const int o = (int)blockIdx.x + 8 * (int)blockIdx.y;
  const int rt = (o & 7) * 4 + ((o >> 3) & 3);  // reuse-dim tile 0..31
  const int ot = o >> 5;                        // other tile 0..7

  const bf16 *A, *B;
  const float* Bv;
  int m0, n0;
  if (z == 0)      { A = qb;  B = Wqb; Bv = bq; m0 = rt * 128; n0 = ot * 128; }
  else if (z == 1) { A = kb;  B = Wkb; Bv = bk; m0 = rt * 128; n0 = ot * 128; }
  else             { A = Wvb; B = vb;  Bv = bv; m0 = ot * 128; n0 = rt * 128; }

  const int tid  = threadIdx.x;
  const int lane = tid & 63;
  const int wv   = tid >> 6;
  const int quad = lane >> 4;
  const int colx = lane & 15;
  const int rm = (wv >> 1) * 64;
  const int rn = (wv & 1) * 64;

  f32x4 acc[4][4];
#pragma unroll
  for (int mi = 0; mi < 4; ++mi)
#pragma unroll
    for (int ni = 0; ni < 4; ++ni) {
      f32x4 zz = {0.f, 0.f, 0.f, 0.f};
      acc[mi][ni] = zz;
    }

  for (int kt = 0; kt < 16; ++kt) {
    const int k0 = kt * 64;
    __syncthreads();
#pragma unroll
    for (int i = 0; i < 4; ++i) {
      const int f = i * 256 + tid;
      const int row = f >> 3;
      const int cc = (f & 7) ^ (row & 7);
      glds16(A + (size_t)(m0 + row) * DM + k0 + cc * 8, sA + f * 8);
      glds16(B + (size_t)(n0 + row) * DM + k0 + cc * 8, sB + f * 8);
    }
    __syncthreads();

    bf16x8 af[4][2], bfr[4][2];
#pragma unroll
    for (int t4 = 0; t4 < 4; ++t4) {
#pragma unroll
      for (int ks = 0; ks < 2; ++ks) {
        const int ra = rm + t4 * 16 + colx;
        af[t4][ks] = *(const bf16x8*)(sA + ra * 64 + (((ks * 4 + quad) ^ (ra & 7)) * 8));
        const int rb = rn + t4 * 16 + colx;
        bfr[t4][ks] = *(const bf16x8*)(sB + rb * 64 + (((ks * 4 + quad) ^ (rb & 7)) * 8));
      }
    }
#pragma unroll
    for (int mi = 0; mi < 4; ++mi)
#pragma unroll
      for (int ni = 0; ni < 4; ++ni) {
        acc[mi][ni] = __builtin_amdgcn_mfma_f32_16x16x32_bf16(af[mi][0], bfr[ni][0], acc[mi][ni], 0, 0, 0);
        acc[mi][ni] = __builtin_amdgcn_mfma_f32_16x16x32_bf16(af[mi][1], bfr[ni][1], acc[mi][ni], 0, 0, 0);
      }
  }

  // epilogue. C/D: row = quad*4+r, col = colx (m89).
  if (z == 2) {
#pragma unroll
    for (int mi = 0; mi < 4; ++mi) {
#pragma unroll
      for (int r = 0; r < 4; ++r) {
        const int m = m0 + rm + mi * 16 + quad * 4 + r;  // Wv row = h*64+d
        const float bias = Bv[m];
        const int hh = m >> 6, d = m & 63;
#pragma unroll
        for (int ni = 0; ni < 4; ++ni) {
          const int n = n0 + rn + ni * 16 + colx;        // v row = b*2048+l
          const int b = n >> 11, l = n & 2047;
          const int lb = l >> 7, li = l & 127;
          const int perm = (li & 15) * 8 + ((li >> 4) & 7);
          Vt[(((size_t)(b * NH + hh) * HD + d) * SEQ) + lb * 128 + perm] =
              (bf16)(acc[mi][ni][r] + bias);
        }
      }
    }
  } else {
    bf16* Out = (z == 0) ? Qh : Kh;
    // 0.125 * log2(e): attn computes exp2 directly (saves a v_mul per score).
    const float scale = (z == 0) ? 0.18033688f : 1.0f;
#pragma unroll
    for (int ni = 0; ni < 4; ++ni) {
      const int n = n0 + rn + ni * 16 + colx;
      const float bias = Bv[n];
#pragma unroll
      for (int mi = 0; mi < 4; ++mi) {
#pragma unroll
        for (int r = 0; r < 4; ++r) {
          const int m = m0 + rm + mi * 16 + quad * 4 + r;
          const float v = (acc[mi][ni][r] + bias) * scale;
          const int b = m >> 11, l = m & 2047, hh = n >> 6, d = n & 63;
          Out[((size_t)(b * NH + hh) * SEQ + l) * HD + d] = (bf16)v;
        }
      }
    }
  }
}

// ---------------------------------------------------------------------------
// Output projection: out = At[4096,1024] @ Wo^T + bo (fp32 store).
// ---------------------------------------------------------------------------
__global__ __launch_bounds__(256, 4) void proj_out(
    const bf16* __restrict__ At, const bf16* __restrict__ Wob,
    const float* __restrict__ bo, float* __restrict__ Out)
{
  __shared__ __align__(16) bf16 sA[128 * 64];
  __shared__ __align__(16) bf16 sB[128 * 64];

  const int o = (int)blockIdx.x + 8 * (int)blockIdx.y;
  const int m0 = ((o & 7) * 4 + ((o >> 3) & 3)) * 128;
  const int n0 = (o >> 5) * 128;

  const int tid  = threadIdx.x;
  const int lane = tid & 63;
  const int wv   = tid >> 6;
  const int quad = lane >> 4;
  const int colx = lane & 15;
  const int rm = (wv >> 1) * 64;
  const int rn = (wv & 1) * 64;

  f32x4 acc[4][4];
#pragma unroll
  for (int mi = 0; mi < 4; ++mi)
#pragma unroll
    for (int ni = 0; ni < 4; ++ni) {
      f32x4 zz = {0.f, 0.f, 0.f, 0.f};
      acc[mi][ni] = zz;
    }

  for (int kt = 0; kt < 16; ++kt) {
    const int k0 = kt * 64;
    __syncthreads();
#pragma unroll
    for (int i = 0; i < 4; ++i) {
      const int f = i * 256 + tid;
      const int row = f >> 3;
      const int cc = (f & 7) ^ (row & 7);
      glds16(At  + (size_t)(m0 + row) * DM + k0 + cc * 8, sA + f * 8);
      glds16(Wob + (size_t)(n0 + row) * DM + k0 + cc * 8, sB + f * 8);
    }
    __syncthreads();

    bf16x8 af[4][2], bfr[4][2];
#pragma unroll
    for (int t4 = 0; t4 < 4; ++t4) {
#pragma unroll
      for (int ks = 0; ks < 2; ++ks) {
        const int ra = rm + t4 * 16 + colx;
        af[t4][ks] = *(const bf16x8*)(sA + ra * 64 + (((ks * 4 + quad) ^ (ra & 7)) * 8));
        const int rb = rn + t4 * 16 + colx;
        bfr[t4][ks] = *(const bf16x8*)(sB + rb * 64 + (((ks * 4 + quad) ^ (rb & 7)) * 8));
      }
    }
#pragma unroll
    for (int mi = 0; mi < 4; ++mi)
#pragma unroll
      for (int ni = 0; ni < 4; ++ni) {
        acc[mi][ni] = __builtin_amdgcn_mfma_f32_16x16x32_bf16(af[mi][0], bfr[ni][0], acc[mi][ni], 0, 0, 0);
        acc[mi][ni] = __builtin_amdgcn_mfma_f32_16x16x32_bf16(af[mi][1], bfr[ni][1], acc[mi][ni], 0, 0, 0);
      }
  }

#pragma unroll
  for (int ni = 0; ni < 4; ++ni) {
    const int n = n0 + rn + ni * 16 + colx;
    const float bias = bo[n];
#pragma unroll
    for (int mi = 0; mi < 4; ++mi) {
#pragma unroll
      for (int r = 0; r < 4; ++r) {
        const int m = m0 + rm + mi * 16 + quad * 4 + r;
        Out[(size_t)m * DM + n] = acc[mi][ni][r] + bias;
      }
    }
  }
}

// ---------------------------------------------------------------------------
// Flash attention R8 (resubmit): glds16 staging + DOUBLE-BUFFERED K/V LDS.
// Tile kc+1's glds16 issues at the top of tile kc's compute; single
// __syncthreads per iter drains vmcnt a full compute-phase after issue ->
// staging latency hidden, barriers 32->16.
// LDS 80KB (2 blocks/CU): sP 16 rows (PV per half), denominator via f32
// butterfly reduce over colx lanes (replaces ones-row MFMA trick).
// Grid (bh, qtile): all 16 q-tile sharers of one bh land on the same XCD
// (id%8=bh%8) -> K/V (2MB/XCD) L2-resident.  exp2 + setprio kept.
// ---------------------------------------------------------------------------
__global__ __launch_bounds__(256, 2) void attn_kernel(
    const bf16* __restrict__ Qh, const bf16* __restrict__ Kh, const bf16* __restrict__ Vt,
    const int* __restrict__ mask, bf16* __restrict__ At)
{
  __shared__ __align__(16) bf16 sK[2][128 * 64];
  __shared__ __align__(16) bf16 sV[2][64 * 128];
  __shared__ __align__(16) bf16 sP[4][16 * 128];

  const int tid  = threadIdx.x;
  const int lane = tid & 63;
  const int wv   = tid >> 6;
  const int quad = lane >> 4;
  const int colx = lane & 15;
  const int bh = blockIdx.x;          // XCD swizzle: sharers of one bh -> same XCD
  const int b  = bh >> 4;
  const int h  = bh & 15;
  const int q0 = blockIdx.y * 128;
  const size_t base  = (size_t)bh * SEQ * HD;
  const size_t baseV = (size_t)bh * HD * SEQ;

  auto issue = [&](int K0, bf16* dK, bf16* dV) {
#pragma unroll
    for (int i = 0; i < 4; ++i) {
      const int f = i * 256 + tid;
      const int kr = f >> 3;
      const int ck = (f & 7) ^ (kr & 7);
      glds16(Kh + base + (size_t)(K0 + kr) * HD + ck * 8, dK + f * 8);
      const int dr = f >> 4;
      const int cv = (f & 15) ^ (dr & 15);
      glds16(Vt + baseV + (size_t)dr * SEQ + K0 + cv * 8, dV + f * 8);
    }
  };

  int mk[8], mkn[8];
  // prologue: tile 0 in flight + mask + Q fragments, then one barrier
  issue(0, sK[0], sV[0]);
#pragma unroll
  for (int nt = 0; nt < 8; ++nt)
    mk[nt] = mask[b * SEQ + nt * 16 + colx];

  bf16x8 qf[2][2];
#pragma unroll
  for (int half = 0; half < 2; ++half) {
    const int qrow = q0 + wv * 32 + half * 16 + colx;
    qf[half][0] = *(const bf16x8*)(Qh + base + (size_t)qrow * HD + quad * 8);
    qf[half][1] = *(const bf16x8*)(Qh + base + (size_t)qrow * HD + 32 + quad * 8);
  }

  f32x4 o[2][4];
  float osum[2][4];
#pragma unroll
  for (int half = 0; half < 2; ++half)
#pragma unroll
    for (int dt = 0; dt < 4; ++dt) {
      f32x4 zz = {0.f, 0.f, 0.f, 0.f};
      o[half][dt] = zz;
      osum[half][dt] = 0.f;
    }
  bf16* sPw = &sP[wv][0];

  __syncthreads();   // tile 0 ready (per-wave vmcnt drained + all waves synced)

  for (int kc = 0; kc < 16; ++kc) {
    const int cur = kc & 1;
    bf16* cK = &sK[cur][0];
    bf16* cV = &sV[cur][0];
    // issue next tile into the just-freed buffer; stays in flight across compute
    if (kc < 15) {
      issue((kc + 1) * 128, &sK[cur ^ 1][0], &sV[cur ^ 1][0]);
#pragma unroll
      for (int nt = 0; nt < 8; ++nt)
        mkn[nt] = mask[b * SEQ + (kc + 1) * 128 + nt * 16 + colx];
    }
    float mreg[8];
#pragma unroll
    for (int nt = 0; nt < 8; ++nt)
      mreg[nt] = (mk[nt] ? -1e30f : 0.0f) - 23.0830917f;  // -16*log2(e)

#pragma unroll
    for (int half = 0; half < 2; ++half) {
      f32x4 s8[8];
      __builtin_amdgcn_s_setprio(1);
#pragma unroll
      for (int nt = 0; nt < 8; ++nt) {
        f32x4 s = {0.f, 0.f, 0.f, 0.f};
        const int krow = nt * 16 + colx;
#pragma unroll
        for (int ks = 0; ks < 2; ++ks) {
          const bf16x8 kf = *(const bf16x8*)(cK + krow * 64 + (((ks * 4 + quad) ^ (krow & 7)) * 8));
          s = __builtin_amdgcn_mfma_f32_16x16x32_bf16(qf[half][ks], kf, s, 0, 0, 0);
        }
        s8[nt] = s;
      }
      __builtin_amdgcn_s_setprio(0);

      float rs[4];
#pragma unroll
      for (int r = 0; r < 4; ++r) {
        bf16x8 pk;
        float rsum = 0.f;
#pragma unroll
        for (int nt = 0; nt < 8; ++nt) {
          const float e = __builtin_amdgcn_exp2f(s8[nt][r] + mreg[nt]);
          pk[nt] = (bf16)e;
          rsum += e;
        }
        const int row = quad * 4 + r;
        *(bf16x8*)(sPw + row * 128 + ((colx ^ row) * 8)) = pk;
        rs[r] = rsum;
      }
      // denominator: butterfly over the 16 colx lanes (f32, exact)
#pragma unroll
      for (int r = 0; r < 4; ++r) {
        rs[r] += __shfl_xor(rs[r], 1);
        rs[r] += __shfl_xor(rs[r], 2);
        rs[r] += __shfl_xor(rs[r], 4);
        rs[r] += __shfl_xor(rs[r], 8);
        osum[half][r] += rs[r];
      }

      __builtin_amdgcn_s_setprio(1);
#pragma unroll
      for (int ks = 0; ks < 4; ++ks) {
        const int ch = ((ks * 4 + quad) ^ colx) * 8;
        const bf16x8 pf = *(const bf16x8*)(sPw + colx * 128 + ch);
#pragma unroll
        for (int dt = 0; dt < 4; ++dt) {
          const bf16x8 vf = *(const bf16x8*)(cV + (dt * 16 + colx) * 128 + ch);
          o[half][dt] = __builtin_amdgcn_mfma_f32_16x16x32_bf16(pf, vf, o[half][dt], 0, 0, 0);
        }
      }
      __builtin_amdgcn_s_setprio(0);
    }

    if (kc < 15) {
#pragma unroll
      for (int nt = 0; nt < 8; ++nt) mk[nt] = mkn[nt];
    }
    __syncthreads();   // everyone done with buf[cur]; next tile's loads drained
  }

#pragma unroll
  for (int half = 0; half < 2; ++half) {
#pragma unroll
    for (int r = 0; r < 4; ++r) {
      const float inv = 1.0f / osum[half][r];
      const int q = q0 + wv * 32 + half * 16 + quad * 4 + r;
#pragma unroll
      for (int dt = 0; dt < 4; ++dt) {
        At[((size_t)(b * SEQ + q)) * DM + h * HD + dt * 16 + colx] =
            (bf16)(o[half][dt][r] * inv);
      }
    }
  }
}

extern "C" void kernel_launch(void* const* d_in, const int* in_sizes, int n_in,
                              void* d_out, int out_size, void* d_ws, size_t ws_size,
                              hipStream_t stream) {
  (void)in_sizes; (void)n_in; (void)out_size; (void)ws_size;
  const float* q    = (const float*)d_in[0];
  const float* k    = (const float*)d_in[1];
  const float* v    = (const float*)d_in[2];
  const int*   mask = (const int*)d_in[3];
  const float* Wq   = (const float*)d_in[4];
  const float* bq   = (const float*)d_in[5];
  const float* Wk   = (const float*)d_in[6];
  const float* bk   = (const float*)d_in[7];
  const float* Wv   = (const float*)d_in[8];
  const float* bv   = (const float*)d_in[9];
  const float* Wo   = (const float*)d_in[10];
  const float* bo   = (const float*)d_in[11];
  float* out = (float*)d_out;

  const size_t T = (size_t)MROWS * DM;   // 4,194,304
  const size_t WT = (size_t)DM * DM;     // 1,048,576
  bf16* ws  = (bf16*)d_ws;
  bf16* qb  = ws;             // later reused as At (qb dead after proj_qkv)
  bf16* kb  = qb + T;
  bf16* vb  = kb + T;
  bf16* Wqb = vb + T;
  bf16* Wkb = Wqb + WT;
  bf16* Wvb = Wkb + WT;
  bf16* Wob = Wvb + WT;
  bf16* Qh  = Wob + WT;
  bf16* Kh  = Qh + T;
  bf16* Vt  = Kh + T;
  bf16* At  = qb;             // alias: safe, qb consumed before attn writes At

  dim3 blk(256);
  conv_all<<<8192, blk, 0, stream>>>(q, k, v, Wq, Wk, Wv, Wo,
                                     qb, kb, vb, Wqb, Wkb, Wvb, Wob);
  proj_qkv<<<dim3(8, 32, 3), blk, 0, stream>>>(qb, kb, vb, Wqb, Wkb, Wvb,
                                               bq, bk, bv, Qh, Kh, Vt);
  // grid = (bh, qtile): blocks sharing K/V co-locate on an XCD
  attn_kernel<<<dim3(32, 16), blk, 0, stream>>>(Qh, Kh, Vt, mask, At);
  proj_out<<<dim3(8, 32), blk, 0, stream>>>(At, Wob, bo, out);
}

// Round 4
// 224.192 us; speedup vs baseline: 1.0054x; 1.0054x over previous
//
#include <hip/hip_runtime.h>
#include <stdint.h>

typedef __bf16 bf16;
typedef __attribute__((ext_vector_type(8))) __bf16 bf16x8;
typedef __attribute__((ext_vector_type(4))) float f32x4;

#define SEQ   2048
#define DM    1024
#define NH    16
#define HD    64
#define MROWS 4096   // B*L

__device__ __forceinline__ void glds16(const bf16* g, bf16* l) {
  __builtin_amdgcn_global_load_lds(
      (__attribute__((address_space(1))) unsigned int*)(g),
      (__attribute__((address_space(3))) unsigned int*)(l),
      16, 0, 0);
}

static __device__ __forceinline__ bf16x8 cvt_f32x8(const float* __restrict__ p) {
  const f32x4 a = *(const f32x4*)p;
  const f32x4 b = *(const f32x4*)(p + 4);
  bf16x8 r;
  r[0] = (bf16)a[0]; r[1] = (bf16)a[1]; r[2] = (bf16)a[2]; r[3] = (bf16)a[3];
  r[4] = (bf16)b[0]; r[5] = (bf16)b[1]; r[6] = (bf16)b[2]; r[7] = (bf16)b[3];
  return r;
}

// ---------------------------------------------------------------------------
// One-pass fp32->bf16 conversion of all 7 tensors (q,k,v,Wq,Wk,Wv,Wo).
// ---------------------------------------------------------------------------
__global__ void conv_all(
    const float* __restrict__ q, const float* __restrict__ k, const float* __restrict__ v,
    const float* __restrict__ wq, const float* __restrict__ wk,
    const float* __restrict__ wv, const float* __restrict__ wo,
    bf16* __restrict__ dq, bf16* __restrict__ dk, bf16* __restrict__ dv,
    bf16* __restrict__ dwq, bf16* __restrict__ dwk, bf16* __restrict__ dwv,
    bf16* __restrict__ dwo)
{
  const size_t c = (size_t)blockIdx.x * 256 + threadIdx.x;
  const float* s; bf16* d; size_t off;
  if (c < 524288)        { s = q;  d = dq;  off = c; }
  else if (c < 1048576)  { s = k;  d = dk;  off = c - 524288; }
  else if (c < 1572864)  { s = v;  d = dv;  off = c - 1048576; }
  else if (c < 1703936)  { s = wq; d = dwq; off = c - 1572864; }
  else if (c < 1835008)  { s = wk; d = dwk; off = c - 1703936; }
  else if (c < 1966080)  { s = wv; d = dwv; off = c - 1835008; }
  else                   { s = wo; d = dwo; off = c - 1966080; }
  *(bf16x8*)(d + off * 8) = cvt_f32x8(s + off * 8);
}

// ---------------------------------------------------------------------------
// Fused QKV projection, all-bf16, single-buffered (32 KB LDS, 4 blocks/CU).
// z=0: Qh = (q@Wq^T+bq)*(0.125*log2e) head layout (attn uses exp2);
// z=1: Kh; z=2: Vt = Wv@v^T+bv, [B,H,64,SEQ] with key'=(l&15)*8+((l>>4)&7).
// ---------------------------------------------------------------------------
__global__ __launch_bounds__(256, 4) void proj_qkv(
    const bf16* __restrict__ qb, const bf16* __restrict__ kb, const bf16* __restrict__ vb,
    const bf16* __restrict__ Wqb, const bf16* __restrict__ Wkb, const bf16* __restrict__ Wvb,
    const float* __restrict__ bq, const float* __restrict__ bk, const float* __restrict__ bv,
    bf16* __restrict__ Qh, bf16* __restrict__ Kh, bf16* __restrict__ Vt)
{
  __shared__ __align__(16) bf16 sA[128 * 64];
  __shared__ __align__(16) bf16 sB[128 * 64];

  const int z = blockIdx.z;
  const int o = (int)blockIdx.x + 8 * (int)blockIdx.y;
  const int rt = (o & 7) * 4 + ((o >> 3) & 3);  // reuse-dim tile 0..31
  const int ot = o >> 5;                        // other tile 0..7

  const bf16 *A, *B;
  const float* Bv;
  int m0, n0;
  if (z == 0)      { A = qb;  B = Wqb; Bv = bq; m0 = rt * 128; n0 = ot * 128; }
  else if (z == 1) { A = kb;  B = Wkb; Bv = bk; m0 = rt * 128; n0 = ot * 128; }
  else             { A = Wvb; B = vb;  Bv = bv; m0 = ot * 128; n0 = rt * 128; }

  const int tid  = threadIdx.x;
  const int lane = tid & 63;
  const int wv   = tid >> 6;
  const int quad = lane >> 4;
  const int colx = lane & 15;
  const int rm = (wv >> 1) * 64;
  const int rn = (wv & 1) * 64;

  f32x4 acc[4][4];
#pragma unroll
  for (int mi = 0; mi < 4; ++mi)
#pragma unroll
    for (int ni = 0; ni < 4; ++ni) {
      f32x4 zz = {0.f, 0.f, 0.f, 0.f};
      acc[mi][ni] = zz;
    }

  for (int kt = 0; kt < 16; ++kt) {
    const int k0 = kt * 64;
    __syncthreads();
#pragma unroll
    for (int i = 0; i < 4; ++i) {
      const int f = i * 256 + tid;
      const int row = f >> 3;
      const int cc = (f & 7) ^ (row & 7);
      glds16(A + (size_t)(m0 + row) * DM + k0 + cc * 8, sA + f * 8);
      glds16(B + (size_t)(n0 + row) * DM + k0 + cc * 8, sB + f * 8);
    }
    __syncthreads();

    bf16x8 af[4][2], bfr[4][2];
#pragma unroll
    for (int t4 = 0; t4 < 4; ++t4) {
#pragma unroll
      for (int ks = 0; ks < 2; ++ks) {
        const int ra = rm + t4 * 16 + colx;
        af[t4][ks] = *(const bf16x8*)(sA + ra * 64 + (((ks * 4 + quad) ^ (ra & 7)) * 8));
        const int rb = rn + t4 * 16 + colx;
        bfr[t4][ks] = *(const bf16x8*)(sB + rb * 64 + (((ks * 4 + quad) ^ (rb & 7)) * 8));
      }
    }
#pragma unroll
    for (int mi = 0; mi < 4; ++mi)
#pragma unroll
      for (int ni = 0; ni < 4; ++ni) {
        acc[mi][ni] = __builtin_amdgcn_mfma_f32_16x16x32_bf16(af[mi][0], bfr[ni][0], acc[mi][ni], 0, 0, 0);
        acc[mi][ni] = __builtin_amdgcn_mfma_f32_16x16x32_bf16(af[mi][1], bfr[ni][1], acc[mi][ni], 0, 0, 0);
      }
  }

  // epilogue. C/D: row = quad*4+r, col = colx (m89).
  if (z == 2) {
#pragma unroll
    for (int mi = 0; mi < 4; ++mi) {
#pragma unroll
      for (int r = 0; r < 4; ++r) {
        const int m = m0 + rm + mi * 16 + quad * 4 + r;  // Wv row = h*64+d
        const float bias = Bv[m];
        const int hh = m >> 6, d = m & 63;
#pragma unroll
        for (int ni = 0; ni < 4; ++ni) {
          const int n = n0 + rn + ni * 16 + colx;        // v row = b*2048+l
          const int b = n >> 11, l = n & 2047;
          const int lb = l >> 7, li = l & 127;
          const int perm = (li & 15) * 8 + ((li >> 4) & 7);
          Vt[(((size_t)(b * NH + hh) * HD + d) * SEQ) + lb * 128 + perm] =
              (bf16)(acc[mi][ni][r] + bias);
        }
      }
    }
  } else {
    bf16* Out = (z == 0) ? Qh : Kh;
    // 0.125 * log2(e): attn computes exp2 directly (saves a v_mul per score).
    const float scale = (z == 0) ? 0.18033688f : 1.0f;
#pragma unroll
    for (int ni = 0; ni < 4; ++ni) {
      const int n = n0 + rn + ni * 16 + colx;
      const float bias = Bv[n];
#pragma unroll
      for (int mi = 0; mi < 4; ++mi) {
#pragma unroll
        for (int r = 0; r < 4; ++r) {
          const int m = m0 + rm + mi * 16 + quad * 4 + r;
          const float v = (acc[mi][ni][r] + bias) * scale;
          const int b = m >> 11, l = m & 2047, hh = n >> 6, d = n & 63;
          Out[((size_t)(b * NH + hh) * SEQ + l) * HD + d] = (bf16)v;
        }
      }
    }
  }
}

// ---------------------------------------------------------------------------
// Output projection: out = At[4096,1024] @ Wo^T + bo (fp32 store).
// ---------------------------------------------------------------------------
__global__ __launch_bounds__(256, 4) void proj_out(
    const bf16* __restrict__ At, const bf16* __restrict__ Wob,
    const float* __restrict__ bo, float* __restrict__ Out)
{
  __shared__ __align__(16) bf16 sA[128 * 64];
  __shared__ __align__(16) bf16 sB[128 * 64];

  const int o = (int)blockIdx.x + 8 * (int)blockIdx.y;
  const int m0 = ((o & 7) * 4 + ((o >> 3) & 3)) * 128;
  const int n0 = (o >> 5) * 128;

  const int tid  = threadIdx.x;
  const int lane = tid & 63;
  const int wv   = tid >> 6;
  const int quad = lane >> 4;
  const int colx = lane & 15;
  const int rm = (wv >> 1) * 64;
  const int rn = (wv & 1) * 64;

  f32x4 acc[4][4];
#pragma unroll
  for (int mi = 0; mi < 4; ++mi)
#pragma unroll
    for (int ni = 0; ni < 4; ++ni) {
      f32x4 zz = {0.f, 0.f, 0.f, 0.f};
      acc[mi][ni] = zz;
    }

  for (int kt = 0; kt < 16; ++kt) {
    const int k0 = kt * 64;
    __syncthreads();
#pragma unroll
    for (int i = 0; i < 4; ++i) {
      const int f = i * 256 + tid;
      const int row = f >> 3;
      const int cc = (f & 7) ^ (row & 7);
      glds16(At  + (size_t)(m0 + row) * DM + k0 + cc * 8, sA + f * 8);
      glds16(Wob + (size_t)(n0 + row) * DM + k0 + cc * 8, sB + f * 8);
    }
    __syncthreads();

    bf16x8 af[4][2], bfr[4][2];
#pragma unroll
    for (int t4 = 0; t4 < 4; ++t4) {
#pragma unroll
      for (int ks = 0; ks < 2; ++ks) {
        const int ra = rm + t4 * 16 + colx;
        af[t4][ks] = *(const bf16x8*)(sA + ra * 64 + (((ks * 4 + quad) ^ (ra & 7)) * 8));
        const int rb = rn + t4 * 16 + colx;
        bfr[t4][ks] = *(const bf16x8*)(sB + rb * 64 + (((ks * 4 + quad) ^ (rb & 7)) * 8));
      }
    }
#pragma unroll
    for (int mi = 0; mi < 4; ++mi)
#pragma unroll
      for (int ni = 0; ni < 4; ++ni) {
        acc[mi][ni] = __builtin_amdgcn_mfma_f32_16x16x32_bf16(af[mi][0], bfr[ni][0], acc[mi][ni], 0, 0, 0);
        acc[mi][ni] = __builtin_amdgcn_mfma_f32_16x16x32_bf16(af[mi][1], bfr[ni][1], acc[mi][ni], 0, 0, 0);
      }
  }

#pragma unroll
  for (int ni = 0; ni < 4; ++ni) {
    const int n = n0 + rn + ni * 16 + colx;
    const float bias = bo[n];
#pragma unroll
    for (int mi = 0; mi < 4; ++mi) {
#pragma unroll
      for (int r = 0; r < 4; ++r) {
        const int m = m0 + rm + mi * 16 + quad * 4 + r;
        Out[(size_t)m * DM + n] = acc[mi][ni][r] + bias;
      }
    }
  }
}

// ---------------------------------------------------------------------------
// Flash attention R9: LDS-traffic halving on top of R8's dbuf+XCD structure.
// R8 post-mortem: FETCH 69.7->12.4MB (XCD win) but dur 57->64us; with 0 bank
// conflicts and both pipes mid-range the limiter is LDS throughput (R8 ~96
// ds-ops/wave/tile). R9 cuts to 48: kf read ONCE (QK both halves interleaved,
// s8[2][8]); V tile cached in regs once/tile (vf[4][4], reused by both
// halves); denominator butterfly deferred to epilogue (lane-local partials).
// ---------------------------------------------------------------------------
__global__ __launch_bounds__(256, 2) void attn_kernel(
    const bf16* __restrict__ Qh, const bf16* __restrict__ Kh, const bf16* __restrict__ Vt,
    const int* __restrict__ mask, bf16* __restrict__ At)
{
  __shared__ __align__(16) bf16 sK[2][128 * 64];
  __shared__ __align__(16) bf16 sV[2][64 * 128];
  __shared__ __align__(16) bf16 sP[4][16 * 128];

  const int tid  = threadIdx.x;
  const int lane = tid & 63;
  const int wv   = tid >> 6;
  const int quad = lane >> 4;
  const int colx = lane & 15;
  const int bh = blockIdx.x;          // XCD swizzle: sharers of one bh -> same XCD
  const int b  = bh >> 4;
  const int h  = bh & 15;
  const int q0 = blockIdx.y * 128;
  const size_t base  = (size_t)bh * SEQ * HD;
  const size_t baseV = (size_t)bh * HD * SEQ;

  auto issue = [&](int K0, bf16* dK, bf16* dV) {
#pragma unroll
    for (int i = 0; i < 4; ++i) {
      const int f = i * 256 + tid;
      const int kr = f >> 3;
      const int ck = (f & 7) ^ (kr & 7);
      glds16(Kh + base + (size_t)(K0 + kr) * HD + ck * 8, dK + f * 8);
      const int dr = f >> 4;
      const int cv = (f & 15) ^ (dr & 15);
      glds16(Vt + baseV + (size_t)dr * SEQ + K0 + cv * 8, dV + f * 8);
    }
  };

  int mk[8];
  // prologue: tile 0 in flight + mask + Q fragments, then one barrier
  issue(0, sK[0], sV[0]);
#pragma unroll
  for (int nt = 0; nt < 8; ++nt)
    mk[nt] = mask[b * SEQ + nt * 16 + colx];

  bf16x8 qf[2][2];
#pragma unroll
  for (int half = 0; half < 2; ++half) {
    const int qrow = q0 + wv * 32 + half * 16 + colx;
    qf[half][0] = *(const bf16x8*)(Qh + base + (size_t)qrow * HD + quad * 8);
    qf[half][1] = *(const bf16x8*)(Qh + base + (size_t)qrow * HD + 32 + quad * 8);
  }

  f32x4 o[2][4];
  float osum[2][4];   // lane-local partial denominators; butterfly at epilogue
#pragma unroll
  for (int half = 0; half < 2; ++half)
#pragma unroll
    for (int dt = 0; dt < 4; ++dt) {
      f32x4 zz = {0.f, 0.f, 0.f, 0.f};
      o[half][dt] = zz;
      osum[half][dt] = 0.f;
    }
  bf16* sPw = &sP[wv][0];

  __syncthreads();   // tile 0 ready

  for (int kc = 0; kc < 16; ++kc) {
    const int cur = kc & 1;
    bf16* cK = &sK[cur][0];
    bf16* cV = &sV[cur][0];

    // mask -> mreg for this tile; mk then freed and refilled with next tile's
    float mreg[8];
#pragma unroll
    for (int nt = 0; nt < 8; ++nt)
      mreg[nt] = (mk[nt] ? -1e30f : 0.0f) - 23.0830917f;  // -16*log2(e)

    // issue next tile into the just-freed buffer; stays in flight all compute
    if (kc < 15) {
      issue((kc + 1) * 128, &sK[cur ^ 1][0], &sV[cur ^ 1][0]);
#pragma unroll
      for (int nt = 0; nt < 8; ++nt)
        mk[nt] = mask[b * SEQ + (kc + 1) * 128 + nt * 16 + colx];
    }

    // ---- QK^T, both halves share each kf read (16 ds_read, 32 MFMA) ----
    f32x4 s8[2][8];
#pragma unroll
    for (int half = 0; half < 2; ++half)
#pragma unroll
      for (int nt = 0; nt < 8; ++nt) {
        f32x4 zz = {0.f, 0.f, 0.f, 0.f};
        s8[half][nt] = zz;
      }
    __builtin_amdgcn_s_setprio(1);
#pragma unroll
    for (int nt = 0; nt < 8; ++nt) {
      const int krow = nt * 16 + colx;
#pragma unroll
      for (int ks = 0; ks < 2; ++ks) {
        const bf16x8 kf = *(const bf16x8*)(cK + krow * 64 + (((ks * 4 + quad) ^ (krow & 7)) * 8));
        s8[0][nt] = __builtin_amdgcn_mfma_f32_16x16x32_bf16(qf[0][ks], kf, s8[0][nt], 0, 0, 0);
        s8[1][nt] = __builtin_amdgcn_mfma_f32_16x16x32_bf16(qf[1][ks], kf, s8[1][nt], 0, 0, 0);
      }
    }
    __builtin_amdgcn_s_setprio(0);

    // ---- V tile -> registers once; reused by both halves (16 ds_read) ----
    bf16x8 vf[4][4];
#pragma unroll
    for (int ks = 0; ks < 4; ++ks) {
      const int ch = ((ks * 4 + quad) ^ colx) * 8;
#pragma unroll
      for (int dt = 0; dt < 4; ++dt)
        vf[ks][dt] = *(const bf16x8*)(cV + (dt * 16 + colx) * 128 + ch);
    }

#pragma unroll
    for (int half = 0; half < 2; ++half) {
      // softmax numerator + lane-local denominator partials (4 ds_write)
#pragma unroll
      for (int r = 0; r < 4; ++r) {
        bf16x8 pk;
        float rsum = 0.f;
#pragma unroll
        for (int nt = 0; nt < 8; ++nt) {
          const float e = __builtin_amdgcn_exp2f(s8[half][nt][r] + mreg[nt]);
          pk[nt] = (bf16)e;
          rsum += e;
        }
        const int row = quad * 4 + r;
        *(bf16x8*)(sPw + row * 128 + ((colx ^ row) * 8)) = pk;
        osum[half][r] += rsum;
      }

      // PV from register-cached V (4 ds_read, 16 MFMA)
      __builtin_amdgcn_s_setprio(1);
#pragma unroll
      for (int ks = 0; ks < 4; ++ks) {
        const int ch = ((ks * 4 + quad) ^ colx) * 8;
        const bf16x8 pf = *(const bf16x8*)(sPw + colx * 128 + ch);
#pragma unroll
        for (int dt = 0; dt < 4; ++dt)
          o[half][dt] = __builtin_amdgcn_mfma_f32_16x16x32_bf16(pf, vf[ks][dt], o[half][dt], 0, 0, 0);
      }
      __builtin_amdgcn_s_setprio(0);
    }

    __syncthreads();   // everyone done with buf[cur]; next tile's loads drained
  }

  // epilogue: one butterfly per (half,r) over the 16 colx lanes, then store
#pragma unroll
  for (int half = 0; half < 2; ++half) {
#pragma unroll
    for (int r = 0; r < 4; ++r) {
      float s = osum[half][r];
      s += __shfl_xor(s, 1);
      s += __shfl_xor(s, 2);
      s += __shfl_xor(s, 4);
      s += __shfl_xor(s, 8);
      const float inv = 1.0f / s;
      const int q = q0 + wv * 32 + half * 16 + quad * 4 + r;
#pragma unroll
      for (int dt = 0; dt < 4; ++dt) {
        At[((size_t)(b * SEQ + q)) * DM + h * HD + dt * 16 + colx] =
            (bf16)(o[half][dt][r] * inv);
      }
    }
  }
}

extern "C" void kernel_launch(void* const* d_in, const int* in_sizes, int n_in,
                              void* d_out, int out_size, void* d_ws, size_t ws_size,
                              hipStream_t stream) {
  (void)in_sizes; (void)n_in; (void)out_size; (void)ws_size;
  const float* q    = (const float*)d_in[0];
  const float* k    = (const float*)d_in[1];
  const float* v    = (const float*)d_in[2];
  const int*   mask = (const int*)d_in[3];
  const float* Wq   = (const float*)d_in[4];
  const float* bq   = (const float*)d_in[5];
  const float* Wk   = (const float*)d_in[6];
  const float* bk   = (const float*)d_in[7];
  const float* Wv   = (const float*)d_in[8];
  const float* bv   = (const float*)d_in[9];
  const float* Wo   = (const float*)d_in[10];
  const float* bo   = (const float*)d_in[11];
  float* out = (float*)d_out;

  const size_t T = (size_t)MROWS * DM;   // 4,194,304
  const size_t WT = (size_t)DM * DM;     // 1,048,576
  bf16* ws  = (bf16*)d_ws;
  bf16* qb  = ws;             // later reused as At (qb dead after proj_qkv)
  bf16* kb  = qb + T;
  bf16* vb  = kb + T;
  bf16* Wqb = vb + T;
  bf16* Wkb = Wqb + WT;
  bf16* Wvb = Wkb + WT;
  bf16* Wob = Wvb + WT;
  bf16* Qh  = Wob + WT;
  bf16* Kh  = Qh + T;
  bf16* Vt  = Kh + T;
  bf16* At  = qb;             // alias: safe, qb consumed before attn writes At

  dim3 blk(256);
  conv_all<<<8192, blk, 0, stream>>>(q, k, v, Wq, Wk, Wv, Wo,
                                     qb, kb, vb, Wqb, Wkb, Wvb, Wob);
  proj_qkv<<<dim3(8, 32, 3), blk, 0, stream>>>(qb, kb, vb, Wqb, Wkb, Wvb,
                                               bq, bk, bv, Qh, Kh, Vt);
  // grid = (bh, qtile): blocks sharing K/V co-locate on an XCD
  attn_kernel<<<dim3(32, 16), blk, 0, stream>>>(Qh, Kh, Vt, mask, At);
  proj_out<<<dim3(8, 32), blk, 0, stream>>>(At, Wob, bo, out);
}

// Round 5
// 209.531 us; speedup vs baseline: 1.0758x; 1.0700x over previous
//
#include <hip/hip_runtime.h>
#include <stdint.h>

typedef __bf16 bf16;
typedef __attribute__((ext_vector_type(8))) __bf16 bf16x8;
typedef __attribute__((ext_vector_type(4))) __bf16 bf16x4;
typedef __attribute__((ext_vector_type(4))) float f32x4;

#define SEQ   2048
#define DM    1024
#define NH    16
#define HD    64
#define MROWS 4096   // B*L

__device__ __forceinline__ void glds16(const bf16* g, bf16* l) {
  __builtin_amdgcn_global_load_lds(
      (__attribute__((address_space(1))) unsigned int*)(g),
      (__attribute__((address_space(3))) unsigned int*)(l),
      16, 0, 0);
}

static __device__ __forceinline__ bf16x8 cvt_f32x8(const float* __restrict__ p) {
  const f32x4 a = *(const f32x4*)p;
  const f32x4 b = *(const f32x4*)(p + 4);
  bf16x8 r;
  r[0] = (bf16)a[0]; r[1] = (bf16)a[1]; r[2] = (bf16)a[2]; r[3] = (bf16)a[3];
  r[4] = (bf16)b[0]; r[5] = (bf16)b[1]; r[6] = (bf16)b[2]; r[7] = (bf16)b[3];
  return r;
}

// ---------------------------------------------------------------------------
// One-pass fp32->bf16 conversion of all 7 tensors (q,k,v,Wq,Wk,Wv,Wo).
// ---------------------------------------------------------------------------
__global__ void conv_all(
    const float* __restrict__ q, const float* __restrict__ k, const float* __restrict__ v,
    const float* __restrict__ wq, const float* __restrict__ wk,
    const float* __restrict__ wv, const float* __restrict__ wo,
    bf16* __restrict__ dq, bf16* __restrict__ dk, bf16* __restrict__ dv,
    bf16* __restrict__ dwq, bf16* __restrict__ dwk, bf16* __restrict__ dwv,
    bf16* __restrict__ dwo)
{
  const size_t c = (size_t)blockIdx.x * 256 + threadIdx.x;
  const float* s; bf16* d; size_t off;
  if (c < 524288)        { s = q;  d = dq;  off = c; }
  else if (c < 1048576)  { s = k;  d = dk;  off = c - 524288; }
  else if (c < 1572864)  { s = v;  d = dv;  off = c - 1048576; }
  else if (c < 1703936)  { s = wq; d = dwq; off = c - 1572864; }
  else if (c < 1835008)  { s = wk; d = dwk; off = c - 1703936; }
  else if (c < 1966080)  { s = wv; d = dwv; off = c - 1835008; }
  else                   { s = wo; d = dwo; off = c - 1966080; }
  *(bf16x8*)(d + off * 8) = cvt_f32x8(s + off * 8);
}

// ---------------------------------------------------------------------------
// Fused QKV projection, all-bf16, single-buffered (32 KB LDS, 4 blocks/CU).
// z=0: Qh = (q@Wq^T+bq)*(0.125*log2e) head layout (attn uses exp2);
// z=1: Kh; z=2: Vt = Wv@v^T+bv, [B,H,64,SEQ], 64-block key permutation
// p=(li&15)*4+((li>>4)&3) so attn's KVBLK=64 P/V fragment key maps align.
// ---------------------------------------------------------------------------
__global__ __launch_bounds__(256, 4) void proj_qkv(
    const bf16* __restrict__ qb, const bf16* __restrict__ kb, const bf16* __restrict__ vb,
    const bf16* __restrict__ Wqb, const bf16* __restrict__ Wkb, const bf16* __restrict__ Wvb,
    const float* __restrict__ bq, const float* __restrict__ bk, const float* __restrict__ bv,
    bf16* __restrict__ Qh, bf16* __restrict__ Kh, bf16* __restrict__ Vt)
{
  __shared__ __align__(16) bf16 sA[128 * 64];
  __shared__ __align__(16) bf16 sB[128 * 64];

  const int z = blockIdx.z;
  const int o = (int)blockIdx.x + 8 * (int)blockIdx.y;
  const int rt = (o & 7) * 4 + ((o >> 3) & 3);  // reuse-dim tile 0..31
  const int ot = o >> 5;                        // other tile 0..7

  const bf16 *A, *B;
  const float* Bv;
  int m0, n0;
  if (z == 0)      { A = qb;  B = Wqb; Bv = bq; m0 = rt * 128; n0 = ot * 128; }
  else if (z == 1) { A = kb;  B = Wkb; Bv = bk; m0 = rt * 128; n0 = ot * 128; }
  else             { A = Wvb; B = vb;  Bv = bv; m0 = ot * 128; n0 = rt * 128; }

  const int tid  = threadIdx.x;
  const int lane = tid & 63;
  const int wv   = tid >> 6;
  const int quad = lane >> 4;
  const int colx = lane & 15;
  const int rm = (wv >> 1) * 64;
  const int rn = (wv & 1) * 64;

  f32x4 acc[4][4];
#pragma unroll
  for (int mi = 0; mi < 4; ++mi)
#pragma unroll
    for (int ni = 0; ni < 4; ++ni) {
      f32x4 zz = {0.f, 0.f, 0.f, 0.f};
      acc[mi][ni] = zz;
    }

  for (int kt = 0; kt < 16; ++kt) {
    const int k0 = kt * 64;
    __syncthreads();
#pragma unroll
    for (int i = 0; i < 4; ++i) {
      const int f = i * 256 + tid;
      const int row = f >> 3;
      const int cc = (f & 7) ^ (row & 7);
      glds16(A + (size_t)(m0 + row) * DM + k0 + cc * 8, sA + f * 8);
      glds16(B + (size_t)(n0 + row) * DM + k0 + cc * 8, sB + f * 8);
    }
    __syncthreads();

    bf16x8 af[4][2], bfr[4][2];
#pragma unroll
    for (int t4 = 0; t4 < 4; ++t4) {
#pragma unroll
      for (int ks = 0; ks < 2; ++ks) {
        const int ra = rm + t4 * 16 + colx;
        af[t4][ks] = *(const bf16x8*)(sA + ra * 64 + (((ks * 4 + quad) ^ (ra & 7)) * 8));
        const int rb = rn + t4 * 16 + colx;
        bfr[t4][ks] = *(const bf16x8*)(sB + rb * 64 + (((ks * 4 + quad) ^ (rb & 7)) * 8));
      }
    }
#pragma unroll
    for (int mi = 0; mi < 4; ++mi)
#pragma unroll
      for (int ni = 0; ni < 4; ++ni) {
        acc[mi][ni] = __builtin_amdgcn_mfma_f32_16x16x32_bf16(af[mi][0], bfr[ni][0], acc[mi][ni], 0, 0, 0);
        acc[mi][ni] = __builtin_amdgcn_mfma_f32_16x16x32_bf16(af[mi][1], bfr[ni][1], acc[mi][ni], 0, 0, 0);
      }
  }

  // epilogue. C/D: row = quad*4+r, col = colx (m89).
  if (z == 2) {
#pragma unroll
    for (int mi = 0; mi < 4; ++mi) {
#pragma unroll
      for (int r = 0; r < 4; ++r) {
        const int m = m0 + rm + mi * 16 + quad * 4 + r;  // Wv row = h*64+d
        const float bias = Bv[m];
        const int hh = m >> 6, d = m & 63;
#pragma unroll
        for (int ni = 0; ni < 4; ++ni) {
          const int n = n0 + rn + ni * 16 + colx;        // v row = b*2048+l
          const int b = n >> 11, l = n & 2047;
          const int lb = l >> 6, li = l & 63;
          const int perm = (li & 15) * 4 + ((li >> 4) & 3);
          Vt[(((size_t)(b * NH + hh) * HD + d) * SEQ) + lb * 64 + perm] =
              (bf16)(acc[mi][ni][r] + bias);
        }
      }
    }
  } else {
    bf16* Out = (z == 0) ? Qh : Kh;
    // 0.125 * log2(e): attn computes exp2 directly (saves a v_mul per score).
    const float scale = (z == 0) ? 0.18033688f : 1.0f;
#pragma unroll
    for (int ni = 0; ni < 4; ++ni) {
      const int n = n0 + rn + ni * 16 + colx;
      const float bias = Bv[n];
#pragma unroll
      for (int mi = 0; mi < 4; ++mi) {
#pragma unroll
        for (int r = 0; r < 4; ++r) {
          const int m = m0 + rm + mi * 16 + quad * 4 + r;
          const float v = (acc[mi][ni][r] + bias) * scale;
          const int b = m >> 11, l = m & 2047, hh = n >> 6, d = n & 63;
          Out[((size_t)(b * NH + hh) * SEQ + l) * HD + d] = (bf16)v;
        }
      }
    }
  }
}

// ---------------------------------------------------------------------------
// Output projection: out = At[4096,1024] @ Wo^T + bo (fp32 store).
// ---------------------------------------------------------------------------
__global__ __launch_bounds__(256, 4) void proj_out(
    const bf16* __restrict__ At, const bf16* __restrict__ Wob,
    const float* __restrict__ bo, float* __restrict__ Out)
{
  __shared__ __align__(16) bf16 sA[128 * 64];
  __shared__ __align__(16) bf16 sB[128 * 64];

  const int o = (int)blockIdx.x + 8 * (int)blockIdx.y;
  const int m0 = ((o & 7) * 4 + ((o >> 3) & 3)) * 128;
  const int n0 = (o >> 5) * 128;

  const int tid  = threadIdx.x;
  const int lane = tid & 63;
  const int wv   = tid >> 6;
  const int quad = lane >> 4;
  const int colx = lane & 15;
  const int rm = (wv >> 1) * 64;
  const int rn = (wv & 1) * 64;

  f32x4 acc[4][4];
#pragma unroll
  for (int mi = 0; mi < 4; ++mi)
#pragma unroll
    for (int ni = 0; ni < 4; ++ni) {
      f32x4 zz = {0.f, 0.f, 0.f, 0.f};
      acc[mi][ni] = zz;
    }

  for (int kt = 0; kt < 16; ++kt) {
    const int k0 = kt * 64;
    __syncthreads();
#pragma unroll
    for (int i = 0; i < 4; ++i) {
      const int f = i * 256 + tid;
      const int row = f >> 3;
      const int cc = (f & 7) ^ (row & 7);
      glds16(At  + (size_t)(m0 + row) * DM + k0 + cc * 8, sA + f * 8);
      glds16(Wob + (size_t)(n0 + row) * DM + k0 + cc * 8, sB + f * 8);
    }
    __syncthreads();

    bf16x8 af[4][2], bfr[4][2];
#pragma unroll
    for (int t4 = 0; t4 < 4; ++t4) {
#pragma unroll
      for (int ks = 0; ks < 2; ++ks) {
        const int ra = rm + t4 * 16 + colx;
        af[t4][ks] = *(const bf16x8*)(sA + ra * 64 + (((ks * 4 + quad) ^ (ra & 7)) * 8));
        const int rb = rn + t4 * 16 + colx;
        bfr[t4][ks] = *(const bf16x8*)(sB + rb * 64 + (((ks * 4 + quad) ^ (rb & 7)) * 8));
      }
    }
#pragma unroll
    for (int mi = 0; mi < 4; ++mi)
#pragma unroll
      for (int ni = 0; ni < 4; ++ni) {
        acc[mi][ni] = __builtin_amdgcn_mfma_f32_16x16x32_bf16(af[mi][0], bfr[ni][0], acc[mi][ni], 0, 0, 0);
        acc[mi][ni] = __builtin_amdgcn_mfma_f32_16x16x32_bf16(af[mi][1], bfr[ni][1], acc[mi][ni], 0, 0, 0);
      }
  }

#pragma unroll
  for (int ni = 0; ni < 4; ++ni) {
    const int n = n0 + rn + ni * 16 + colx;
    const float bias = bo[n];
#pragma unroll
    for (int mi = 0; mi < 4; ++mi) {
#pragma unroll
      for (int r = 0; r < 4; ++r) {
        const int m = m0 + rm + mi * 16 + quad * 4 + r;
        Out[(size_t)m * DM + n] = acc[mi][ni][r] + bias;
      }
    }
  }
}

// ---------------------------------------------------------------------------
// Flash attention R10: occupancy push. R9 post-mortem: 43% no-issue cycles,
// 8 waves/CU — serial QK->exp->pack->PV chain with only 2 waves/SIMD to
// fill bubbles. R10: KVBLK 128->64 => LDS 80->40KB (sK 2x8K, sV 2x8K,
// sP 4x2K) => 3 blocks/CU (12 waves, +50% TLP, launch_bounds(256,3)).
// Structure otherwise identical to R9 (dbuf, 1 barrier/tile, XCD grid,
// exp2, setprio, reg-cached V, deferred denominator butterfly).
// sP write is 8B/lane (4 keys), swizzled at 16B granularity.
// ---------------------------------------------------------------------------
__global__ __launch_bounds__(256, 3) void attn_kernel(
    const bf16* __restrict__ Qh, const bf16* __restrict__ Kh, const bf16* __restrict__ Vt,
    const int* __restrict__ mask, bf16* __restrict__ At)
{
  __shared__ __align__(16) bf16 sK[2][64 * 64];
  __shared__ __align__(16) bf16 sV[2][64 * 64];
  __shared__ __align__(16) bf16 sP[4][16 * 64];

  const int tid  = threadIdx.x;
  const int lane = tid & 63;
  const int wv   = tid >> 6;
  const int quad = lane >> 4;
  const int colx = lane & 15;
  const int bh = blockIdx.x;          // XCD swizzle: sharers of one bh -> same XCD
  const int b  = bh >> 4;
  const int h  = bh & 15;
  const int q0 = blockIdx.y * 128;
  const size_t base  = (size_t)bh * SEQ * HD;
  const size_t baseV = (size_t)bh * HD * SEQ;

  auto issue = [&](int K0, bf16* dK, bf16* dV) {
#pragma unroll
    for (int i = 0; i < 2; ++i) {
      const int f = i * 256 + tid;          // 0..511
      const int kr = f >> 3;                // key row 0..63
      const int ck = (f & 7) ^ (kr & 7);
      glds16(Kh + base + (size_t)(K0 + kr) * HD + ck * 8, dK + f * 8);
      const int dr = f >> 3;                // d row 0..63
      const int cv = (f & 7) ^ (dr & 7);
      glds16(Vt + baseV + (size_t)dr * SEQ + K0 + cv * 8, dV + f * 8);
    }
  };

  int mk[4];
  // prologue: tile 0 in flight + mask + Q fragments, then one barrier
  issue(0, sK[0], sV[0]);
#pragma unroll
  for (int nt = 0; nt < 4; ++nt)
    mk[nt] = mask[b * SEQ + nt * 16 + colx];

  bf16x8 qf[2][2];
#pragma unroll
  for (int half = 0; half < 2; ++half) {
    const int qrow = q0 + wv * 32 + half * 16 + colx;
    qf[half][0] = *(const bf16x8*)(Qh + base + (size_t)qrow * HD + quad * 8);
    qf[half][1] = *(const bf16x8*)(Qh + base + (size_t)qrow * HD + 32 + quad * 8);
  }

  f32x4 o[2][4];
  float osum[2][4];   // lane-local partial denominators; butterfly at epilogue
#pragma unroll
  for (int half = 0; half < 2; ++half)
#pragma unroll
    for (int dt = 0; dt < 4; ++dt) {
      f32x4 zz = {0.f, 0.f, 0.f, 0.f};
      o[half][dt] = zz;
      osum[half][dt] = 0.f;
    }
  bf16* sPw = &sP[wv][0];
  // sP addressing: lane's 8B slot at row q: byte = q*128 + ((colx>>1)^(q&7))*16 + (colx&1)*8
  // read 16B chunk c at row colx:          byte = colx*128 + ((c^(colx&7))*16)

  __syncthreads();   // tile 0 ready

  for (int kc = 0; kc < 32; ++kc) {
    const int cur = kc & 1;
    bf16* cK = &sK[cur][0];
    bf16* cV = &sV[cur][0];

    float mreg[4];
#pragma unroll
    for (int nt = 0; nt < 4; ++nt)
      mreg[nt] = (mk[nt] ? -1e30f : 0.0f) - 23.0830917f;  // -16*log2(e)

    // issue next tile into the just-freed buffer; stays in flight all compute
    if (kc < 31) {
      issue((kc + 1) * 64, &sK[cur ^ 1][0], &sV[cur ^ 1][0]);
#pragma unroll
      for (int nt = 0; nt < 4; ++nt)
        mk[nt] = mask[b * SEQ + (kc + 1) * 64 + nt * 16 + colx];
    }

    // ---- QK^T, both halves share each kf read (8 ds_read, 16 MFMA) ----
    f32x4 s8[2][4];
#pragma unroll
    for (int half = 0; half < 2; ++half)
#pragma unroll
      for (int nt = 0; nt < 4; ++nt) {
        f32x4 zz = {0.f, 0.f, 0.f, 0.f};
        s8[half][nt] = zz;
      }
    __builtin_amdgcn_s_setprio(1);
#pragma unroll
    for (int nt = 0; nt < 4; ++nt) {
      const int krow = nt * 16 + colx;
#pragma unroll
      for (int ks = 0; ks < 2; ++ks) {
        const bf16x8 kf = *(const bf16x8*)(cK + krow * 64 + (((ks * 4 + quad) ^ (krow & 7)) * 8));
        s8[0][nt] = __builtin_amdgcn_mfma_f32_16x16x32_bf16(qf[0][ks], kf, s8[0][nt], 0, 0, 0);
        s8[1][nt] = __builtin_amdgcn_mfma_f32_16x16x32_bf16(qf[1][ks], kf, s8[1][nt], 0, 0, 0);
      }
    }
    __builtin_amdgcn_s_setprio(0);

    // ---- V tile -> registers once; reused by both halves (8 ds_read) ----
    bf16x8 vf[2][4];
#pragma unroll
    for (int ks = 0; ks < 2; ++ks) {
#pragma unroll
      for (int dt = 0; dt < 4; ++dt) {
        const int row = dt * 16 + colx;
        vf[ks][dt] = *(const bf16x8*)(cV + row * 64 + (((ks * 4 + quad) ^ (row & 7)) * 8));
      }
    }

#pragma unroll
    for (int half = 0; half < 2; ++half) {
      // softmax numerator + lane-local denominator partials (4x 8B ds_write)
#pragma unroll
      for (int r = 0; r < 4; ++r) {
        bf16x4 pk;
        float rsum = 0.f;
#pragma unroll
        for (int nt = 0; nt < 4; ++nt) {
          const float e = __builtin_amdgcn_exp2f(s8[half][nt][r] + mreg[nt]);
          pk[nt] = (bf16)e;
          rsum += e;
        }
        const int row = quad * 4 + r;
        *(bf16x4*)(sPw + row * 64 + (((colx >> 1) ^ (row & 7)) * 8) + (colx & 1) * 4) = pk;
        osum[half][r] += rsum;
      }

      // PV from register-cached V (2 ds_read, 8 MFMA)
      __builtin_amdgcn_s_setprio(1);
#pragma unroll
      for (int ks = 0; ks < 2; ++ks) {
        const bf16x8 pf = *(const bf16x8*)(sPw + colx * 64 + (((ks * 4 + quad) ^ (colx & 7)) * 8));
#pragma unroll
        for (int dt = 0; dt < 4; ++dt)
          o[half][dt] = __builtin_amdgcn_mfma_f32_16x16x32_bf16(pf, vf[ks][dt], o[half][dt], 0, 0, 0);
      }
      __builtin_amdgcn_s_setprio(0);
    }

    __syncthreads();   // everyone done with buf[cur]; next tile's loads drained
  }

  // epilogue: one butterfly per (half,r) over the 16 colx lanes, then store
#pragma unroll
  for (int half = 0; half < 2; ++half) {
#pragma unroll
    for (int r = 0; r < 4; ++r) {
      float s = osum[half][r];
      s += __shfl_xor(s, 1);
      s += __shfl_xor(s, 2);
      s += __shfl_xor(s, 4);
      s += __shfl_xor(s, 8);
      const float inv = 1.0f / s;
      const int q = q0 + wv * 32 + half * 16 + quad * 4 + r;
#pragma unroll
      for (int dt = 0; dt < 4; ++dt) {
        At[((size_t)(b * SEQ + q)) * DM + h * HD + dt * 16 + colx] =
            (bf16)(o[half][dt][r] * inv);
      }
    }
  }
}

extern "C" void kernel_launch(void* const* d_in, const int* in_sizes, int n_in,
                              void* d_out, int out_size, void* d_ws, size_t ws_size,
                              hipStream_t stream) {
  (void)in_sizes; (void)n_in; (void)out_size; (void)ws_size;
  const float* q    = (const float*)d_in[0];
  const float* k    = (const float*)d_in[1];
  const float* v    = (const float*)d_in[2];
  const int*   mask = (const int*)d_in[3];
  const float* Wq   = (const float*)d_in[4];
  const float* bq   = (const float*)d_in[5];
  const float* Wk   = (const float*)d_in[6];
  const float* bk   = (const float*)d_in[7];
  const float* Wv   = (const float*)d_in[8];
  const float* bv   = (const float*)d_in[9];
  const float* Wo   = (const float*)d_in[10];
  const float* bo   = (const float*)d_in[11];
  float* out = (float*)d_out;

  const size_t T = (size_t)MROWS * DM;   // 4,194,304
  const size_t WT = (size_t)DM * DM;     // 1,048,576
  bf16* ws  = (bf16*)d_ws;
  bf16* qb  = ws;             // later reused as At (qb dead after proj_qkv)
  bf16* kb  = qb + T;
  bf16* vb  = kb + T;
  bf16* Wqb = vb + T;
  bf16* Wkb = Wqb + WT;
  bf16* Wvb = Wkb + WT;
  bf16* Wob = Wvb + WT;
  bf16* Qh  = Wob + WT;
  bf16* Kh  = Qh + T;
  bf16* Vt  = Kh + T;
  bf16* At  = qb;             // alias: safe, qb consumed before attn writes At

  dim3 blk(256);
  conv_all<<<8192, blk, 0, stream>>>(q, k, v, Wq, Wk, Wv, Wo,
                                     qb, kb, vb, Wqb, Wkb, Wvb, Wob);
  proj_qkv<<<dim3(8, 32, 3), blk, 0, stream>>>(qb, kb, vb, Wqb, Wkb, Wvb,
                                               bq, bk, bv, Qh, Kh, Vt);
  // grid = (bh, qtile): blocks sharing K/V co-locate on an XCD
  attn_kernel<<<dim3(32, 16), blk, 0, stream>>>(Qh, Kh, Vt, mask, At);
  proj_out<<<dim3(8, 32), blk, 0, stream>>>(At, Wob, bo, out);
}